// Round 8
// baseline (152.681 us; speedup 1.0000x reference)
//
#include <hip/hip_runtime.h>
#include <math.h>

#define NN 4096
#define ROWS_PER_BLOCK 16   // consecutive rows; block sweeps 256 KB sequentially
#define BLK 256

// ---------- small helpers ----------

__device__ __forceinline__ float4 ld4(const float* __restrict__ p, int t) {
    return reinterpret_cast<const float4*>(p)[t];
}
__device__ __forceinline__ void st4(float* __restrict__ p, int t, float4 v) {
    reinterpret_cast<float4*>(p)[t] = v;
}
__device__ __forceinline__ float4 add4(float4 a, float4 b) {
    return make_float4(a.x + b.x, a.y + b.y, a.z + b.z, a.w + b.w);
}

// async global->LDS, 16B per lane; LDS dst is wave-uniform base (+lane*16 implicit)
// AUX cache policy: 0 = normal, 2 = NT (non-temporal; no L2/LLC retention).
typedef const __attribute__((address_space(1))) unsigned int* gas1_u32;
typedef __attribute__((address_space(3))) unsigned int* las3_u32;
template<int AUX>
__device__ __forceinline__ void async16(const float* g, float* l) {
    __builtin_amdgcn_global_load_lds((gas1_u32)(const void*)g, (las3_u32)(void*)l, 16, 0, AUX);
}

// stage one full 16 KB row into LDS, block-sequential: wave w covers bytes [4w,4w+4) KB
template<int AUX>
__device__ __forceinline__ void stage_row(const float* __restrict__ W, int row,
                                          float* __restrict__ buf, int wave, int lane) {
    const float* g = W + (size_t)row * NN + wave * 1024 + lane * 4;
    float* l = buf + wave * 1024;
    async16<AUX>(g,       l);
    async16<AUX>(g + 256, l + 256);
    async16<AUX>(g + 512, l + 512);
    async16<AUX>(g + 768, l + 768);
}

// dot(row-in-LDS, x-in-regs) -> wave-reduced partial (valid in lane 0)
__device__ __forceinline__ float dot_row(const float* __restrict__ buf,
                                         const float4 xr[4], int tid) {
    const float4* b4 = reinterpret_cast<const float4*>(buf);
    float p = 0.f;
    #pragma unroll
    for (int i = 0; i < 4; ++i) {
        float4 w = b4[i * 256 + tid];
        p = fmaf(w.x, xr[i].x, p);
        p = fmaf(w.y, xr[i].y, p);
        p = fmaf(w.z, xr[i].z, p);
        p = fmaf(w.w, xr[i].w, p);
    }
    #pragma unroll
    for (int off = 32; off > 0; off >>= 1) p += __shfl_down(p, off, 64);
    return p;
}

struct LNStat { float mu, rstd; };

// block-wide LN stats for 256 threads x 16 elems (4 float4 per thread)
__device__ __forceinline__ LNStat stats256(const float4 v[4], float* rbuf) {
    float s = 0.f, ss = 0.f;
    #pragma unroll
    for (int i = 0; i < 4; ++i) {
        s  += v[i].x + v[i].y + v[i].z + v[i].w;
        ss += v[i].x * v[i].x + v[i].y * v[i].y + v[i].z * v[i].z + v[i].w * v[i].w;
    }
    #pragma unroll
    for (int off = 32; off > 0; off >>= 1) {
        s  += __shfl_down(s,  off, 64);
        ss += __shfl_down(ss, off, 64);
    }
    const int wave = threadIdx.x >> 6;
    const int lane = threadIdx.x & 63;
    if (lane == 0) { rbuf[wave] = s; rbuf[4 + wave] = ss; }
    __syncthreads();
    if (threadIdx.x == 0) {
        rbuf[8] = rbuf[0] + rbuf[1] + rbuf[2] + rbuf[3];
        rbuf[9] = rbuf[4] + rbuf[5] + rbuf[6] + rbuf[7];
    }
    __syncthreads();
    LNStat o;
    o.mu = rbuf[8] * (1.0f / NN);
    float var = rbuf[9] * (1.0f / NN) - o.mu * o.mu;
    o.rstd = rsqrtf(var + 1e-5f);
    __syncthreads();   // safe rbuf reuse
    return o;
}

__device__ __forceinline__ float4 ln_apply(float4 v, LNStat st, float4 g, float4 b) {
    return make_float4((v.x - st.mu) * st.rstd * g.x + b.x,
                       (v.y - st.mu) * st.rstd * g.y + b.y,
                       (v.z - st.mu) * st.rstd * g.z + b.z,
                       (v.w - st.mu) * st.rstd * g.w + b.w);
}

__device__ __forceinline__ float4 relu4(float4 v) {
    return make_float4(fmaxf(v.x, 0.f), fmaxf(v.y, 0.f), fmaxf(v.z, 0.f), fmaxf(v.w, 0.f));
}

// ---------- GEMV core: sequential-sweep, row-at-a-time double buffer ----------
// Block owns 16 consecutive rows (256 KB contiguous). Per step: stage row j+1
// while computing row j from LDS against x in registers. AUX = cache policy.

template<int AUX>
__device__ __forceinline__ void gemv_core(const float* __restrict__ W,
                                          const float* __restrict__ x,
                                          const float* __restrict__ xadd,
                                          float* __restrict__ y,
                                          float* t0, float* t1, float* sbuf) {
    const int tid  = threadIdx.x;
    const int wave = tid >> 6;
    const int lane = tid & 63;
    const int r0 = blockIdx.x * ROWS_PER_BLOCK;

    stage_row<AUX>(W, r0, t0, wave, lane);

    float4 xr[4];
    const float4* x4 = reinterpret_cast<const float4*>(x);
    #pragma unroll
    for (int i = 0; i < 4; ++i) xr[i] = x4[i * 256 + tid];
    if (xadd) {
        const float4* a4 = reinterpret_cast<const float4*>(xadd);
        #pragma unroll
        for (int i = 0; i < 4; ++i) xr[i] = add4(xr[i], a4[i * 256 + tid]);
    }
    __syncthreads();   // t0 staged (vmcnt drain), xr loaded

    #pragma unroll 1
    for (int j = 0; j < ROWS_PER_BLOCK; j += 2) {
        if (tid == 0 && j > 0) y[r0 + j - 1] = sbuf[4] + sbuf[5] + sbuf[6] + sbuf[7];
        if (j + 1 < ROWS_PER_BLOCK) stage_row<AUX>(W, r0 + j + 1, t1, wave, lane);
        {
            float p = dot_row(t0, xr, tid);
            if (lane == 0) sbuf[wave] = p;
        }
        __syncthreads();
        if (tid == 0) y[r0 + j] = sbuf[0] + sbuf[1] + sbuf[2] + sbuf[3];
        if (j + 2 < ROWS_PER_BLOCK) stage_row<AUX>(W, r0 + j + 2, t0, wave, lane);
        {
            float p = dot_row(t1, xr, tid);
            if (lane == 0) sbuf[4 + wave] = p;
        }
        __syncthreads();
    }
    if (tid == 0) y[r0 + ROWS_PER_BLOCK - 1] = sbuf[4] + sbuf[5] + sbuf[6] + sbuf[7];
}

// last-block detection: release-fence + device atomic; returns true in the one
// block that finished last (its whole 256-thread block then runs the epilogue).
__device__ __forceinline__ bool last_block(int* counter, int total, int* flagbuf) {
    if (threadIdx.x == 0) {
        __threadfence();                       // release y-writes (cross-XCD)
        int old = atomicAdd(counter, 1);
        *flagbuf = (old == total - 1);
    }
    __syncthreads();
    bool last = (*flagbuf != 0);
    if (last) __threadfence();                 // acquire other blocks' y-writes
    return last;
}

// ---------- Stage A + fused phase2 ----------
// mv1 = W_H1_H1 @ h1_prev; mv2 = W_H2_H2 @ h2_prev; mv3 = W_I_H1 @ (input_raw + b_i)
// phase2: h1_p2 = relu(LN(mv3 + LN(mv1) + bias_h1)); h2_p2 = relu(LN(LN(mv2) + bias_h2))
__global__ __launch_bounds__(BLK) void gemv_stageA(
    const float* __restrict__ W_H1_H1, const float* __restrict__ h1_prev,
    const float* __restrict__ W_H2_H2, const float* __restrict__ h2_prev,
    const float* __restrict__ W_I_H1,  const float* __restrict__ input_raw,
    const float* __restrict__ b_i,
    float* __restrict__ mv1, float* __restrict__ mv2, float* __restrict__ mv3,
    const float* __restrict__ bias_h1, const float* __restrict__ bias_h2,
    const float* __restrict__ g_h1, const float* __restrict__ bln_h1,
    const float* __restrict__ g_h2, const float* __restrict__ bln_h2,
    float* __restrict__ h1_p2, float* __restrict__ h2_p2,
    int* __restrict__ counter)
{
    __shared__ float t0[NN], t1[NN];   // 16 KB each (one row)
    __shared__ float sbuf[16];
    __shared__ int   flagbuf;
    const float* W; const float* x; const float* xadd; float* y;
    if (blockIdx.y == 0)      { W = W_H1_H1; x = h1_prev;   xadd = nullptr; y = mv1; }
    else if (blockIdx.y == 1) { W = W_H2_H2; x = h2_prev;   xadd = nullptr; y = mv2; }
    else                      { W = W_I_H1;  x = input_raw; xadd = b_i;     y = mv3; }
    gemv_core<2>(W, x, xadd, y, t0, t1, sbuf);   // AUX=2 -> NT streaming

    if (!last_block(counter, 3 * (NN / ROWS_PER_BLOCK), &flagbuf)) return;

    const int t = threadIdx.x;
    float4 g[4], b[4], v[4];
    // chain H1
    #pragma unroll
    for (int i = 0; i < 4; ++i) {
        const int j = i * 256 + t;
        g[i] = ld4(g_h1, j); b[i] = ld4(bln_h1, j); v[i] = ld4(mv1, j);
    }
    LNStat s = stats256(v, sbuf);
    #pragma unroll
    for (int i = 0; i < 4; ++i) {
        const int j = i * 256 + t;
        v[i] = add4(add4(ld4(mv3, j), ln_apply(v[i], s, g[i], b[i])), ld4(bias_h1, j));
    }
    s = stats256(v, sbuf);
    #pragma unroll
    for (int i = 0; i < 4; ++i) st4(h1_p2, i * 256 + t, relu4(ln_apply(v[i], s, g[i], b[i])));
    // chain H2
    #pragma unroll
    for (int i = 0; i < 4; ++i) {
        const int j = i * 256 + t;
        g[i] = ld4(g_h2, j); b[i] = ld4(bln_h2, j); v[i] = ld4(mv2, j);
    }
    s = stats256(v, sbuf);
    #pragma unroll
    for (int i = 0; i < 4; ++i)
        v[i] = add4(ln_apply(v[i], s, g[i], b[i]), ld4(bias_h2, i * 256 + t));
    s = stats256(v, sbuf);
    #pragma unroll
    for (int i = 0; i < 4; ++i) st4(h2_p2, i * 256 + t, relu4(ln_apply(v[i], s, g[i], b[i])));
}

// ---------- Stage B + fused phase3 ----------
// mv4 = W_H2_H1 @ h2_p2; mv5 = W_H1_H2 @ h1_p2
// phase3: h1_f = relu(LN(mv4 + bias_h1)); h2_f = relu(LN(mv5 + bias_h2))
__global__ __launch_bounds__(BLK) void gemv_stageB(
    const float* __restrict__ W_H2_H1, const float* __restrict__ h2_p2,
    const float* __restrict__ W_H1_H2, const float* __restrict__ h1_p2,
    float* __restrict__ mv4, float* __restrict__ mv5,
    const float* __restrict__ bias_h1, const float* __restrict__ bias_h2,
    const float* __restrict__ g_h1, const float* __restrict__ bln_h1,
    const float* __restrict__ g_h2, const float* __restrict__ bln_h2,
    float* __restrict__ h1_f, float* __restrict__ h2_f,
    int* __restrict__ counter)
{
    __shared__ float t0[NN], t1[NN];
    __shared__ float sbuf[16];
    __shared__ int   flagbuf;
    const float* W; const float* x; float* y;
    if (blockIdx.y == 0) { W = W_H2_H1; x = h2_p2; y = mv4; }
    else                 { W = W_H1_H2; x = h1_p2; y = mv5; }
    gemv_core<0>(W, x, nullptr, y, t0, t1, sbuf);

    if (!last_block(counter, 2 * (NN / ROWS_PER_BLOCK), &flagbuf)) return;

    const int t = threadIdx.x;
    float4 g[4], b[4], v[4];
    #pragma unroll
    for (int i = 0; i < 4; ++i) {
        const int j = i * 256 + t;
        g[i] = ld4(g_h1, j); b[i] = ld4(bln_h1, j);
        v[i] = add4(ld4(mv4, j), ld4(bias_h1, j));
    }
    LNStat s = stats256(v, sbuf);
    #pragma unroll
    for (int i = 0; i < 4; ++i) st4(h1_f, i * 256 + t, relu4(ln_apply(v[i], s, g[i], b[i])));
    #pragma unroll
    for (int i = 0; i < 4; ++i) {
        const int j = i * 256 + t;
        g[i] = ld4(g_h2, j); b[i] = ld4(bln_h2, j);
        v[i] = add4(ld4(mv5, j), ld4(bias_h2, j));
    }
    s = stats256(v, sbuf);
    #pragma unroll
    for (int i = 0; i < 4; ++i) st4(h2_f, i * 256 + t, relu4(ln_apply(v[i], s, g[i], b[i])));
}

// ---------- Stage C + fused final ----------
// mv6 = W_H1_O @ h1_f; mv7 = W_H2_O @ h2_f
// final: out = tanh(LN(bln_o + mv6 + mv7 + bias_o) * g_o + bln_o)
__global__ __launch_bounds__(BLK) void gemv_stageC(
    const float* __restrict__ W_H1_O, const float* __restrict__ h1_f,
    const float* __restrict__ W_H2_O, const float* __restrict__ h2_f,
    float* __restrict__ mv6, float* __restrict__ mv7,
    const float* __restrict__ bias_o, const float* __restrict__ bln_o,
    const float* __restrict__ g_o,
    float* __restrict__ out,
    int* __restrict__ counter)
{
    __shared__ float t0[NN], t1[NN];
    __shared__ float sbuf[16];
    __shared__ int   flagbuf;
    const float* W; const float* x; float* y;
    if (blockIdx.y == 0) { W = W_H1_O; x = h1_f; y = mv6; }
    else                 { W = W_H2_O; x = h2_f; y = mv7; }
    gemv_core<0>(W, x, nullptr, y, t0, t1, sbuf);

    if (!last_block(counter, 2 * (NN / ROWS_PER_BLOCK), &flagbuf)) return;

    const int t = threadIdx.x;
    float4 g[4], b[4], v[4];
    #pragma unroll
    for (int i = 0; i < 4; ++i) {
        const int j = i * 256 + t;
        g[i] = ld4(g_o, j); b[i] = ld4(bln_o, j);
        v[i] = add4(add4(b[i], ld4(mv6, j)), add4(ld4(mv7, j), ld4(bias_o, j)));
    }
    LNStat s = stats256(v, sbuf);
    #pragma unroll
    for (int i = 0; i < 4; ++i) {
        float4 r = ln_apply(v[i], s, g[i], b[i]);
        st4(out, i * 256 + t,
            make_float4(tanhf(r.x), tanhf(r.y), tanhf(r.z), tanhf(r.w)));
    }
}

// ---------- launch ----------

extern "C" void kernel_launch(void* const* d_in, const int* in_sizes, int n_in,
                              void* d_out, int out_size, void* d_ws, size_t ws_size,
                              hipStream_t stream) {
    const float* input_raw = (const float*)d_in[0];
    const float* h1_prev   = (const float*)d_in[1];
    const float* h2_prev   = (const float*)d_in[2];
    const float* W_I_H1    = (const float*)d_in[3];
    const float* W_H1_H1   = (const float*)d_in[4];
    const float* W_H1_H2   = (const float*)d_in[5];
    const float* W_H2_H1   = (const float*)d_in[6];
    const float* W_H2_H2   = (const float*)d_in[7];
    const float* W_H1_O    = (const float*)d_in[8];
    const float* W_H2_O    = (const float*)d_in[9];
    const float* bias_h1   = (const float*)d_in[10];
    const float* bias_h2   = (const float*)d_in[11];
    const float* bias_o    = (const float*)d_in[12];
    // d_in[13] = g_i (unused: LN(zeros) == beta)
    const float* b_i       = (const float*)d_in[14];
    const float* g_h1      = (const float*)d_in[15];
    const float* bln_h1    = (const float*)d_in[16];
    const float* g_h2      = (const float*)d_in[17];
    const float* bln_h2    = (const float*)d_in[18];
    const float* g_o       = (const float*)d_in[19];
    const float* bln_o     = (const float*)d_in[20];

    float* ws    = (float*)d_ws;
    float* mv1   = ws;
    float* mv2   = ws + 1 * NN;
    float* mv3   = ws + 2 * NN;
    float* h1_p2 = ws + 3 * NN;
    float* h2_p2 = ws + 4 * NN;
    float* mv4   = ws + 5 * NN;
    float* mv5   = ws + 6 * NN;
    float* h1_f  = ws + 7 * NN;
    float* h2_f  = ws + 8 * NN;
    float* mv6   = ws + 9 * NN;
    float* mv7   = ws + 10 * NN;
    int*   counters = (int*)(ws + 12 * NN);   // 3 ints, zeroed per call

    hipMemsetAsync(counters, 0, 3 * sizeof(int), stream);

    const int gx = NN / ROWS_PER_BLOCK;  // 256 blocks per matrix

    gemv_stageA<<<dim3(gx, 3), BLK, 0, stream>>>(
        W_H1_H1, h1_prev, W_H2_H2, h2_prev, W_I_H1, input_raw, b_i,
        mv1, mv2, mv3, bias_h1, bias_h2, g_h1, bln_h1, g_h2, bln_h2,
        h1_p2, h2_p2, counters + 0);

    gemv_stageB<<<dim3(gx, 2), BLK, 0, stream>>>(
        W_H2_H1, h2_p2, W_H1_H2, h1_p2, mv4, mv5,
        bias_h1, bias_h2, g_h1, bln_h1, g_h2, bln_h2,
        h1_f, h2_f, counters + 1);

    gemv_stageC<<<dim3(gx, 2), BLK, 0, stream>>>(
        W_H1_O, h1_f, W_H2_O, h2_f, mv6, mv7,
        bias_o, bln_o, g_o, (float*)d_out, counters + 2);
}

// Round 9
// 86.873 us; speedup vs baseline: 1.7575x; 1.7575x over previous
//
#include <hip/hip_runtime.h>
#include <math.h>

#define NN 4096
#define ROWS_PER_BLOCK 16
#define GX 256              // blocks per matrix; block b owns rows {b + j*GX}
#define BLK 256

// ---------- small helpers ----------

__device__ __forceinline__ float4 ld4(const float* __restrict__ p, int t) {
    return reinterpret_cast<const float4*>(p)[t];
}
__device__ __forceinline__ void st4(float* __restrict__ p, int t, float4 v) {
    reinterpret_cast<float4*>(p)[t] = v;
}
__device__ __forceinline__ float4 add4(float4 a, float4 b) {
    return make_float4(a.x + b.x, a.y + b.y, a.z + b.z, a.w + b.w);
}

// async global->LDS, 16B per lane; LDS dst is wave-uniform base (+lane*16 implicit)
// AUX cache policy: 0 = normal, 2 = NT (non-temporal; no L2/LLC retention).
typedef const __attribute__((address_space(1))) unsigned int* gas1_u32;
typedef __attribute__((address_space(3))) unsigned int* las3_u32;
template<int AUX>
__device__ __forceinline__ void async16(const float* g, float* l) {
    __builtin_amdgcn_global_load_lds((gas1_u32)(const void*)g, (las3_u32)(void*)l, 16, 0, AUX);
}

// stage one full 16 KB row into LDS: wave w covers bytes [4w,4w+4) KB
template<int AUX>
__device__ __forceinline__ void stage_row(const float* __restrict__ W, int row,
                                          float* __restrict__ buf, int wave, int lane) {
    const float* g = W + (size_t)row * NN + wave * 1024 + lane * 4;
    float* l = buf + wave * 1024;
    async16<AUX>(g,       l);
    async16<AUX>(g + 256, l + 256);
    async16<AUX>(g + 512, l + 512);
    async16<AUX>(g + 768, l + 768);
}

// dot(row-in-LDS, x-in-regs) -> wave-reduced partial (valid in lane 0)
__device__ __forceinline__ float dot_row(const float* __restrict__ buf,
                                         const float4 xr[4], int tid) {
    const float4* b4 = reinterpret_cast<const float4*>(buf);
    float p = 0.f;
    #pragma unroll
    for (int i = 0; i < 4; ++i) {
        float4 w = b4[i * 256 + tid];
        p = fmaf(w.x, xr[i].x, p);
        p = fmaf(w.y, xr[i].y, p);
        p = fmaf(w.z, xr[i].z, p);
        p = fmaf(w.w, xr[i].w, p);
    }
    #pragma unroll
    for (int off = 32; off > 0; off >>= 1) p += __shfl_down(p, off, 64);
    return p;
}

// block-wide (sum, sumsq) reduction, blockDim.x == 1024 (16 waves)
__device__ __forceinline__ float2 block_reduce2(float s, float ss, float* sbuf) {
    #pragma unroll
    for (int off = 32; off > 0; off >>= 1) {
        s  += __shfl_down(s,  off, 64);
        ss += __shfl_down(ss, off, 64);
    }
    const int wave = threadIdx.x >> 6;
    const int lane = threadIdx.x & 63;
    if (lane == 0) { sbuf[wave] = s; sbuf[16 + wave] = ss; }
    __syncthreads();
    float rs = 0.f, rss = 0.f;
    if (threadIdx.x < 16) { rs = sbuf[threadIdx.x]; rss = sbuf[16 + threadIdx.x]; }
    if (wave == 0) {
        #pragma unroll
        for (int off = 8; off > 0; off >>= 1) {
            rs  += __shfl_down(rs,  off, 64);
            rss += __shfl_down(rss, off, 64);
        }
        if (lane == 0) { sbuf[0] = rs; sbuf[1] = rss; }
    }
    __syncthreads();
    float2 r = make_float2(sbuf[0], sbuf[1]);
    __syncthreads();
    return r;
}

struct LNStat { float mu, rstd; };

__device__ __forceinline__ LNStat ln_stats(float4 v, float* sbuf) {
    float s  = v.x + v.y + v.z + v.w;
    float ss = v.x * v.x + v.y * v.y + v.z * v.z + v.w * v.w;
    float2 r = block_reduce2(s, ss, sbuf);
    LNStat o;
    o.mu = r.x * (1.0f / NN);
    float var = r.y * (1.0f / NN) - o.mu * o.mu;
    o.rstd = rsqrtf(var + 1e-5f);
    return o;
}

__device__ __forceinline__ float4 ln_apply(float4 v, LNStat st, float4 g, float4 b) {
    return make_float4((v.x - st.mu) * st.rstd * g.x + b.x,
                       (v.y - st.mu) * st.rstd * g.y + b.y,
                       (v.z - st.mu) * st.rstd * g.z + b.z,
                       (v.w - st.mu) * st.rstd * g.w + b.w);
}

__device__ __forceinline__ float4 relu4(float4 v) {
    return make_float4(fmaxf(v.x, 0.f), fmaxf(v.y, 0.f), fmaxf(v.z, 0.f), fmaxf(v.w, 0.f));
}

// ---------- GEMV core: chip-wide moving-window sweep ----------
// Block b owns rows {b + j*GX}. At step j, ALL blocks of a matrix read rows
// [j*GX, (j+1)*GX) -- one contiguous 4 MB window sweeping the matrix front to
// back (copy-shaped address stream -> DRAM page locality), instead of 768
// independent per-block streams. Double-buffered via LDS; x in registers.

template<int AUX>
__device__ __forceinline__ void gemv_core(const float* __restrict__ W,
                                          const float* __restrict__ x,
                                          const float* __restrict__ xadd,
                                          float* __restrict__ y,
                                          float* t0, float* t1, float* sbuf) {
    const int tid  = threadIdx.x;
    const int wave = tid >> 6;
    const int lane = tid & 63;
    const int r0 = blockIdx.x;          // rows r0 + j*GX

    stage_row<AUX>(W, r0, t0, wave, lane);

    float4 xr[4];
    const float4* x4 = reinterpret_cast<const float4*>(x);
    #pragma unroll
    for (int i = 0; i < 4; ++i) xr[i] = x4[i * 256 + tid];
    if (xadd) {
        const float4* a4 = reinterpret_cast<const float4*>(xadd);
        #pragma unroll
        for (int i = 0; i < 4; ++i) xr[i] = add4(xr[i], a4[i * 256 + tid]);
    }
    __syncthreads();   // t0 staged (vmcnt drain), xr loaded

    #pragma unroll 1
    for (int j = 0; j < ROWS_PER_BLOCK; j += 2) {
        if (tid == 0 && j > 0) y[r0 + (j - 1) * GX] = sbuf[4] + sbuf[5] + sbuf[6] + sbuf[7];
        if (j + 1 < ROWS_PER_BLOCK) stage_row<AUX>(W, r0 + (j + 1) * GX, t1, wave, lane);
        {
            float p = dot_row(t0, xr, tid);
            if (lane == 0) sbuf[wave] = p;
        }
        __syncthreads();
        if (tid == 0) y[r0 + j * GX] = sbuf[0] + sbuf[1] + sbuf[2] + sbuf[3];
        if (j + 2 < ROWS_PER_BLOCK) stage_row<AUX>(W, r0 + (j + 2) * GX, t0, wave, lane);
        {
            float p = dot_row(t1, xr, tid);
            if (lane == 0) sbuf[4 + wave] = p;
        }
        __syncthreads();
    }
    if (tid == 0) y[r0 + (ROWS_PER_BLOCK - 1) * GX] = sbuf[4] + sbuf[5] + sbuf[6] + sbuf[7];
}

// Stage A: mv1 = W_H1_H1 @ h1_prev; mv2 = W_H2_H2 @ h2_prev; mv3 = W_I_H1 @ (input_raw + b_i)
// NT streaming: 192 MB pass through without evicting the L3-resident B/C weights.
__global__ __launch_bounds__(BLK) void gemv_stageA(
    const float* __restrict__ W_H1_H1, const float* __restrict__ h1_prev,
    const float* __restrict__ W_H2_H2, const float* __restrict__ h2_prev,
    const float* __restrict__ W_I_H1,  const float* __restrict__ input_raw,
    const float* __restrict__ b_i,
    float* __restrict__ mv1, float* __restrict__ mv2, float* __restrict__ mv3)
{
    __shared__ float t0[NN], t1[NN];   // 16 KB each (one row)
    __shared__ float sbuf[8];
    const float* W; const float* x; const float* xadd; float* y;
    if (blockIdx.y == 0)      { W = W_H1_H1; x = h1_prev;   xadd = nullptr; y = mv1; }
    else if (blockIdx.y == 1) { W = W_H2_H2; x = h2_prev;   xadd = nullptr; y = mv2; }
    else                      { W = W_I_H1;  x = input_raw; xadd = b_i;     y = mv3; }
    gemv_core<2>(W, x, xadd, y, t0, t1, sbuf);   // AUX=2 -> NT
}

// Pair of independent GEMVs (stages B and C) — default caching (L3-resident)
__global__ __launch_bounds__(BLK) void gemv_pair(
    const float* __restrict__ Wa, const float* __restrict__ xa, float* __restrict__ ya,
    const float* __restrict__ Wb, const float* __restrict__ xb, float* __restrict__ yb)
{
    __shared__ float t0[NN], t1[NN];
    __shared__ float sbuf[8];
    const float* W; const float* x; float* y;
    if (blockIdx.y == 0) { W = Wa; x = xa; y = ya; }
    else                 { W = Wb; x = xb; y = yb; }
    gemv_core<0>(W, x, nullptr, y, t0, t1, sbuf);
}

// ---------- Phase 2: two independent LN chains, one block each ----------
__global__ __launch_bounds__(1024) void phase2_kernel(
    const float* __restrict__ mv1, const float* __restrict__ mv2, const float* __restrict__ mv3,
    const float* __restrict__ bias_h1, const float* __restrict__ bias_h2,
    const float* __restrict__ g_h1, const float* __restrict__ bln_h1,
    const float* __restrict__ g_h2, const float* __restrict__ bln_h2,
    float* __restrict__ h1_p2, float* __restrict__ h2_p2)
{
    __shared__ float sbuf[32];
    const int t = threadIdx.x;
    if (blockIdx.x == 0) {
        float4 g = ld4(g_h1, t), b = ld4(bln_h1, t);
        float4 v = ld4(mv1, t);
        LNStat s1 = ln_stats(v, sbuf);
        float4 fb = ln_apply(v, s1, g, b);
        float4 tt = add4(add4(ld4(mv3, t), fb), ld4(bias_h1, t));
        LNStat s2 = ln_stats(tt, sbuf);
        st4(h1_p2, t, relu4(ln_apply(tt, s2, g, b)));
    } else {
        float4 g = ld4(g_h2, t), b = ld4(bln_h2, t);
        float4 v = ld4(mv2, t);
        LNStat s1 = ln_stats(v, sbuf);
        float4 fb = ln_apply(v, s1, g, b);
        float4 tt = add4(fb, ld4(bias_h2, t));
        LNStat s2 = ln_stats(tt, sbuf);
        st4(h2_p2, t, relu4(ln_apply(tt, s2, g, b)));
    }
}

// ---------- Phase 3 norms: two independent LNs, one block each ----------
__global__ __launch_bounds__(1024) void phase3_kernel(
    const float* __restrict__ mv4, const float* __restrict__ mv5,
    const float* __restrict__ bias_h1, const float* __restrict__ bias_h2,
    const float* __restrict__ g_h1, const float* __restrict__ bln_h1,
    const float* __restrict__ g_h2, const float* __restrict__ bln_h2,
    float* __restrict__ h1_f, float* __restrict__ h2_f)
{
    __shared__ float sbuf[32];
    const int t = threadIdx.x;
    const float* mv;  const float* bias; const float* g; const float* b; float* out;
    if (blockIdx.x == 0) { mv = mv4; bias = bias_h1; g = g_h1; b = bln_h1; out = h1_f; }
    else                 { mv = mv5; bias = bias_h2; g = g_h2; b = bln_h2; out = h2_f; }
    float4 v = add4(ld4(mv, t), ld4(bias, t));
    LNStat s = ln_stats(v, sbuf);
    st4(out, t, relu4(ln_apply(v, s, ld4(g, t), ld4(b, t))));
}

// ---------- Final: o = tanh(LN(bln_o + mv6 + mv7 + bias_o, g_o, bln_o)) ----------
__global__ __launch_bounds__(1024) void final_kernel(
    const float* __restrict__ mv6, const float* __restrict__ mv7,
    const float* __restrict__ bias_o, const float* __restrict__ bln_o,
    const float* __restrict__ g_o,
    float* __restrict__ out)
{
    __shared__ float sbuf[32];
    const int t = threadIdx.x;
    float4 v = add4(add4(ld4(bln_o, t), ld4(mv6, t)), add4(ld4(mv7, t), ld4(bias_o, t)));
    LNStat s = ln_stats(v, sbuf);
    float4 r = ln_apply(v, s, ld4(g_o, t), ld4(bln_o, t));
    st4(out, t, make_float4(tanhf(r.x), tanhf(r.y), tanhf(r.z), tanhf(r.w)));
}

// ---------- launch ----------

extern "C" void kernel_launch(void* const* d_in, const int* in_sizes, int n_in,
                              void* d_out, int out_size, void* d_ws, size_t ws_size,
                              hipStream_t stream) {
    const float* input_raw = (const float*)d_in[0];
    const float* h1_prev   = (const float*)d_in[1];
    const float* h2_prev   = (const float*)d_in[2];
    const float* W_I_H1    = (const float*)d_in[3];
    const float* W_H1_H1   = (const float*)d_in[4];
    const float* W_H1_H2   = (const float*)d_in[5];
    const float* W_H2_H1   = (const float*)d_in[6];
    const float* W_H2_H2   = (const float*)d_in[7];
    const float* W_H1_O    = (const float*)d_in[8];
    const float* W_H2_O    = (const float*)d_in[9];
    const float* bias_h1   = (const float*)d_in[10];
    const float* bias_h2   = (const float*)d_in[11];
    const float* bias_o    = (const float*)d_in[12];
    // d_in[13] = g_i (unused: LN(zeros) == beta)
    const float* b_i       = (const float*)d_in[14];
    const float* g_h1      = (const float*)d_in[15];
    const float* bln_h1    = (const float*)d_in[16];
    const float* g_h2      = (const float*)d_in[17];
    const float* bln_h2    = (const float*)d_in[18];
    const float* g_o       = (const float*)d_in[19];
    const float* bln_o     = (const float*)d_in[20];

    float* ws    = (float*)d_ws;
    float* mv1   = ws;
    float* mv2   = ws + 1 * NN;
    float* mv3   = ws + 2 * NN;
    float* h1_p2 = ws + 3 * NN;
    float* h2_p2 = ws + 4 * NN;
    float* mv4   = ws + 5 * NN;
    float* mv5   = ws + 6 * NN;
    float* h1_f  = ws + 7 * NN;
    float* h2_f  = ws + 8 * NN;
    float* mv6   = ws + 9 * NN;
    float* mv7   = ws + 10 * NN;

    // Stage A: 3 independent GEMVs (NT weight streaming, moving-window sweep)
    gemv_stageA<<<dim3(GX, 3), BLK, 0, stream>>>(
        W_H1_H1, h1_prev, W_H2_H2, h2_prev, W_I_H1, input_raw, b_i, mv1, mv2, mv3);

    // Phase 2 LN chains
    phase2_kernel<<<2, 1024, 0, stream>>>(
        mv1, mv2, mv3, bias_h1, bias_h2, g_h1, bln_h1, g_h2, bln_h2, h1_p2, h2_p2);

    // Stage B: mv4 = W_H2_H1 @ h2_p2 ; mv5 = W_H1_H2 @ h1_p2
    gemv_pair<<<dim3(GX, 2), BLK, 0, stream>>>(
        W_H2_H1, h2_p2, mv4, W_H1_H2, h1_p2, mv5);

    // Phase 3 norms
    phase3_kernel<<<2, 1024, 0, stream>>>(
        mv4, mv5, bias_h1, bias_h2, g_h1, bln_h1, g_h2, bln_h2, h1_f, h2_f);

    // Stage C: mv6 = W_H1_O @ h1_f ; mv7 = W_H2_O @ h2_f
    gemv_pair<<<dim3(GX, 2), BLK, 0, stream>>>(
        W_H1_O, h1_f, mv6, W_H2_O, h2_f, mv7);

    // Final output
    final_kernel<<<1, 1024, 0, stream>>>(
        mv6, mv7, bias_o, bln_o, g_o, (float*)d_out);
}